// Round 4
// baseline (192.076 us; speedup 1.0000x reference)
//
#include <hip/hip_runtime.h>
#include <hip/hip_bf16.h>

// Problem constants
#define B_ 2
#define T_ 2048
#define C_ 1024
#define H_ 16
#define D_ 64
#define M_ROWS (B_ * T_)      // 4096
#define N_QKV (3 * C_)        // 3072
#define QKS (2 * C_)          // q/k buffer row stride = 2048

typedef __bf16 bf16x8 __attribute__((ext_vector_type(8)));
typedef float f32x4 __attribute__((ext_vector_type(4)));

// 0.125 (1/sqrt(64)) * log2(e): softmax in base-2, scale folded in.
#define SC 0.18033688011112042f

// async global->LDS, 16B per lane. LDS dest = wave-uniform base + lane*16.
__device__ __forceinline__ void gl_lds16(const __bf16* g, __bf16* l) {
    __builtin_amdgcn_global_load_lds(
        (const __attribute__((address_space(1))) unsigned int*)g,
        (__attribute__((address_space(3))) unsigned int*)l, 16, 0, 0);
}

// ---------------------------------------------------------------------------
// Pre-pass 1: fp32 -> bf16 convert (x -> xb). 8 elems/thread.
// ---------------------------------------------------------------------------
__global__ __launch_bounds__(256) void conv_bf16(const float* __restrict__ in,
                                                 __bf16* __restrict__ out, int n8)
{
    int i = blockIdx.x * 256 + threadIdx.x;
    if (i >= n8) return;
    const float4* p = (const float4*)(in + (size_t)i * 8);
    float4 a = p[0], b = p[1];
    __bf16 v[8] = {(__bf16)a.x, (__bf16)a.y, (__bf16)a.z, (__bf16)a.w,
                   (__bf16)b.x, (__bf16)b.y, (__bf16)b.z, (__bf16)b.w};
    *(uint4*)(out + (size_t)i * 8) = *(uint4*)v;
}

// ---------------------------------------------------------------------------
// Pre-pass 2 (merged): both weights [K][N] fp32 -> [N][K] bf16.
// grid (16, 64): y<48 -> Wqkv (N=3072), else Wproj (N=1024). K=1024.
// ---------------------------------------------------------------------------
__global__ __launch_bounds__(256) void transp_w2(
    const float* __restrict__ Wqkv, const float* __restrict__ Wproj,
    __bf16* __restrict__ Wqkvt, __bf16* __restrict__ Wprojt)
{
    __shared__ __bf16 Ts[64 * 72];
    const int tid = threadIdx.x;
    const int gy = blockIdx.y;
    const float* W; __bf16* Wt; int N, n0;
    if (gy < 48) { W = Wqkv;  Wt = Wqkvt;  N = N_QKV; n0 = gy * 64; }
    else         { W = Wproj; Wt = Wprojt; N = C_;    n0 = (gy - 48) * 64; }
    const int k0 = blockIdx.x * 64;
#pragma unroll
    for (int i = 0; i < 4; ++i) {
        int f = i * 256 + tid;
        int r = f >> 4, c4 = (f & 15) * 4;
        float4 v = *(const float4*)(W + (size_t)(k0 + r) * N + n0 + c4);
        Ts[(c4 + 0) * 72 + r] = (__bf16)v.x;
        Ts[(c4 + 1) * 72 + r] = (__bf16)v.y;
        Ts[(c4 + 2) * 72 + r] = (__bf16)v.z;
        Ts[(c4 + 3) * 72 + r] = (__bf16)v.w;
    }
    __syncthreads();
#pragma unroll
    for (int i = 0; i < 2; ++i) {
        int f = i * 256 + tid;
        int n = f >> 3, c8 = (f & 7) * 8;
        *(uint4*)(Wt + (size_t)(n0 + n) * C_ + k0 + c8) = *(const uint4*)&Ts[n * 72 + c8];
    }
}

// ---------------------------------------------------------------------------
// GEMM1 (fused): qkv = xb @ Wqkvt^T + bqkv.
// q,k columns -> qk buffer [4096, 2048] bf16; v columns -> vt [B*C][T] bf16
// transposed directly from the C/D fragment (lane holds fixed col, 4 rows).
// ---------------------------------------------------------------------------
#define GBK 64

__global__ __launch_bounds__(256) void gemm_qkv(
    const __bf16* __restrict__ A, const __bf16* __restrict__ Bt,
    const float* __restrict__ bias, __bf16* __restrict__ qk,
    __bf16* __restrict__ vt)
{
    __shared__ __bf16 As[128 * GBK];
    __shared__ __bf16 Bs[128 * GBK];

    const int tid  = threadIdx.x;
    const int m0   = blockIdx.x * 128;
    const int n0   = blockIdx.y * 128;
    const int w    = tid >> 6;
    const int lane = tid & 63;
    const int quad = lane >> 4;
    const int l16  = lane & 15;
    const int wr   = (w >> 1) * 64;
    const int wc   = (w & 1) * 64;
    const int K = C_, N = N_QKV;

    const int srow = w * 32 + (lane >> 3);
    const int sseg = ((lane & 7) ^ (lane >> 3)) * 8;
    const __bf16* Ag = A + (size_t)(m0 + srow) * K + sseg;
    const __bf16* Bg = Bt + (size_t)(n0 + srow) * K + sseg;

    f32x4 acc[4][4] = {};

    for (int k0 = 0; k0 < K; k0 += GBK) {
#pragma unroll
        for (int i = 0; i < 4; ++i) {
            gl_lds16(Ag + k0 + (size_t)(i * 8) * K, &As[(w * 32 + i * 8) * GBK]);
            gl_lds16(Bg + k0 + (size_t)(i * 8) * K, &Bs[(w * 32 + i * 8) * GBK]);
        }
        __syncthreads();
#pragma unroll
        for (int kk = 0; kk < 2; ++kk) {
            bf16x8 af[4], bf[4];
#pragma unroll
            for (int mi = 0; mi < 4; ++mi)
                af[mi] = *(const bf16x8*)&As[(wr + mi * 16 + l16) * GBK +
                                             (((kk * 4 + quad) ^ (l16 & 7)) * 8)];
#pragma unroll
            for (int ni = 0; ni < 4; ++ni)
                bf[ni] = *(const bf16x8*)&Bs[(wc + ni * 16 + l16) * GBK +
                                             (((kk * 4 + quad) ^ (l16 & 7)) * 8)];
#pragma unroll
            for (int mi = 0; mi < 4; ++mi)
#pragma unroll
                for (int ni = 0; ni < 4; ++ni)
                    acc[mi][ni] = __builtin_amdgcn_mfma_f32_16x16x32_bf16(
                        af[mi], bf[ni], acc[mi][ni], 0, 0, 0);
        }
        __syncthreads();
    }

    if (n0 < 2 * C_) {
        // q/k: row-major store into qk (stride 2048)
#pragma unroll
        for (int mi = 0; mi < 4; ++mi) {
#pragma unroll
            for (int ni = 0; ni < 4; ++ni) {
                int col = n0 + wc + ni * 16 + l16;
                float bv = bias[col];
#pragma unroll
                for (int r = 0; r < 4; ++r) {
                    int row = m0 + wr + mi * 16 + quad * 4 + r;
                    qk[(size_t)row * QKS + col] = (__bf16)(acc[mi][ni][r] + bv);
                }
            }
        }
    } else {
        // v: transposed store into vt[(b*C + c)][t]
        const int bb = m0 >> 11;
        const int tb = (m0 & (T_ - 1)) + wr;
#pragma unroll
        for (int mi = 0; mi < 4; ++mi) {
#pragma unroll
            for (int ni = 0; ni < 4; ++ni) {
                int col = n0 + wc + ni * 16 + l16;
                float bv = bias[col];
                int c = col - 2 * C_;
                int t0 = tb + mi * 16 + quad * 4;
                __bf16 pb[4];
#pragma unroll
                for (int r = 0; r < 4; ++r)
                    pb[r] = (__bf16)(acc[mi][ni][r] + bv);
                *(uint2*)&vt[((size_t)bb * C_ + c) * T_ + t0] = *(uint2*)pb;
            }
        }
    }
}

// ---------------------------------------------------------------------------
// GEMM2: out = att @ Wprojt^T + bproj (fp32 out).
// ---------------------------------------------------------------------------
__global__ __launch_bounds__(256) void gemm_proj(
    const __bf16* __restrict__ A, const __bf16* __restrict__ Bt,
    const float* __restrict__ bias, float* __restrict__ C)
{
    __shared__ __bf16 As[128 * GBK];
    __shared__ __bf16 Bs[128 * GBK];

    const int tid  = threadIdx.x;
    const int m0   = blockIdx.x * 128;
    const int n0   = blockIdx.y * 128;
    const int w    = tid >> 6;
    const int lane = tid & 63;
    const int quad = lane >> 4;
    const int l16  = lane & 15;
    const int wr   = (w >> 1) * 64;
    const int wc   = (w & 1) * 64;
    const int K = C_, N = C_;

    const int srow = w * 32 + (lane >> 3);
    const int sseg = ((lane & 7) ^ (lane >> 3)) * 8;
    const __bf16* Ag = A + (size_t)(m0 + srow) * K + sseg;
    const __bf16* Bg = Bt + (size_t)(n0 + srow) * K + sseg;

    f32x4 acc[4][4] = {};

    for (int k0 = 0; k0 < K; k0 += GBK) {
#pragma unroll
        for (int i = 0; i < 4; ++i) {
            gl_lds16(Ag + k0 + (size_t)(i * 8) * K, &As[(w * 32 + i * 8) * GBK]);
            gl_lds16(Bg + k0 + (size_t)(i * 8) * K, &Bs[(w * 32 + i * 8) * GBK]);
        }
        __syncthreads();
#pragma unroll
        for (int kk = 0; kk < 2; ++kk) {
            bf16x8 af[4], bf[4];
#pragma unroll
            for (int mi = 0; mi < 4; ++mi)
                af[mi] = *(const bf16x8*)&As[(wr + mi * 16 + l16) * GBK +
                                             (((kk * 4 + quad) ^ (l16 & 7)) * 8)];
#pragma unroll
            for (int ni = 0; ni < 4; ++ni)
                bf[ni] = *(const bf16x8*)&Bs[(wc + ni * 16 + l16) * GBK +
                                             (((kk * 4 + quad) ^ (l16 & 7)) * 8)];
#pragma unroll
            for (int mi = 0; mi < 4; ++mi)
#pragma unroll
                for (int ni = 0; ni < 4; ++ni)
                    acc[mi][ni] = __builtin_amdgcn_mfma_f32_16x16x32_bf16(
                        af[mi], bf[ni], acc[mi][ni], 0, 0, 0);
        }
        __syncthreads();
    }

#pragma unroll
    for (int mi = 0; mi < 4; ++mi) {
#pragma unroll
        for (int ni = 0; ni < 4; ++ni) {
            int col = n0 + wc + ni * 16 + l16;
            float bv = bias[col];
#pragma unroll
            for (int r = 0; r < 4; ++r) {
                int row = m0 + wr + mi * 16 + quad * 4 + r;
                C[(size_t)row * N + col] = acc[mi][ni][r] + bv;
            }
        }
    }
}

// ---------------------------------------------------------------------------
// Flash attention v4: 128-q tiles, 4 waves x 32 q/wave (two q-groups sharing
// one K/V fragment read), XCD-pinned heads (blockIdx.x = bh), complementary
// heavy/light block layers for balance, no-max base-2 softmax, S^T trick,
// double-buffered K/V staging, group-0 skip on the fully-masked last tile.
// ---------------------------------------------------------------------------
__global__ __launch_bounds__(256) void attn_kernel(
    const __bf16* __restrict__ qk, const __bf16* __restrict__ vt,
    __bf16* __restrict__ out)
{
    __shared__ __bf16 Qs[128 * 64];       // 16 KB
    __shared__ __bf16 KVs[4][64 * 64];    // 32 KB (K0,V0,K1,V1)
    __shared__ __bf16 Ps[4][2][16 * 64];  // 16 KB, per-wave per-group

    const int tid  = threadIdx.x;
    const int bh   = blockIdx.x;          // 0..31 -> XCD = bh % 8
    const int j    = blockIdx.y;          // 0..15: layer 0 heavy, layer 1 light
    const int qt   = (j < 8) ? (15 - j) : (j - 8);
    const int b    = bh >> 4;
    const int h    = bh & 15;
    const int w    = tid >> 6;
    const int lane = tid & 63;
    const int quad = lane >> 4;
    const int l16  = lane & 15;
    const int lxor = l16 & 7;

    const int srow = lane >> 3;
    const int sseg = ((lane & 7) ^ srow) * 8;
    const int nkt  = 2 * qt + 2;

    // ---- stage Q tile (128 rows x 64 d): wave w stages rows w*32..w*32+31 ----
    {
        const __bf16* Qg = qk + (size_t)(b * T_ + qt * 128 + w * 32 + srow) * QKS
                         + (size_t)h * 64 + sseg;
#pragma unroll
        for (int i = 0; i < 4; ++i)
            gl_lds16(Qg + (size_t)(i * 8) * QKS, &Qs[(w * 32 + i * 8) * 64]);
        const __bf16* Kg = qk + (size_t)(b * T_ + w * 16 + srow) * QKS
                         + C_ + (size_t)h * 64 + sseg;
        gl_lds16(Kg, &KVs[0][(w * 16) * 64]);
        gl_lds16(Kg + (size_t)8 * QKS, &KVs[0][(w * 16 + 8) * 64]);
        const __bf16* Vg = vt + ((size_t)(b * H_ + h) * 64 + w * 16 + srow) * T_ + sseg;
        gl_lds16(Vg, &KVs[1][(w * 16) * 64]);
        gl_lds16(Vg + (size_t)8 * T_, &KVs[1][(w * 16 + 8) * 64]);
    }
    __syncthreads();

    // ---- hoist Q fragments: group g covers q-rows g*64 + w*16 + l16 ----
    bf16x8 qf[2][2];
#pragma unroll
    for (int g = 0; g < 2; ++g)
#pragma unroll
        for (int kk = 0; kk < 2; ++kk)
            qf[g][kk] = *(const bf16x8*)&Qs[(g * 64 + w * 16 + l16) * 64 +
                                            (((kk * 4 + quad) ^ lxor) * 8)];

    f32x4 o[2][4] = {};
    float lacc[2] = {0.f, 0.f};

    for (int kt = 0; kt < nkt; ++kt) {
        const __bf16* Ks = KVs[(kt & 1) * 2];
        const __bf16* Vs = KVs[(kt & 1) * 2 + 1];

        if (kt + 1 < nkt) {
            int nb = ((kt + 1) & 1) * 2;
            const __bf16* Kg = qk + (size_t)(b * T_ + (kt + 1) * 64 + w * 16 + srow) * QKS
                             + C_ + (size_t)h * 64 + sseg;
            gl_lds16(Kg, &KVs[nb][(w * 16) * 64]);
            gl_lds16(Kg + (size_t)8 * QKS, &KVs[nb][(w * 16 + 8) * 64]);
            const __bf16* Vg = vt + ((size_t)(b * H_ + h) * 64 + w * 16 + srow) * T_
                             + (kt + 1) * 64 + sseg;
            gl_lds16(Vg, &KVs[nb + 1][(w * 16) * 64]);
            gl_lds16(Vg + (size_t)8 * T_, &KVs[nb + 1][(w * 16 + 8) * 64]);
        }

        // ---- per group: S^T = K Q^T, mask, exp2, pack P ----
#pragma unroll
        for (int g = 0; g < 2; ++g) {
            if (g == 0 && kt == nkt - 1) continue;   // fully masked for group 0
            f32x4 s[4] = {};
#pragma unroll
            for (int ni = 0; ni < 4; ++ni) {
#pragma unroll
                for (int kk = 0; kk < 2; ++kk) {
                    bf16x8 kf = *(const bf16x8*)&Ks[(ni * 16 + l16) * 64 +
                                                    (((kk * 4 + quad) ^ lxor) * 8)];
                    s[ni] = __builtin_amdgcn_mfma_f32_16x16x32_bf16(kf, qf[g][kk], s[ni], 0, 0, 0);
                }
            }
            if (kt == 2 * qt + g) {   // diagonal tile for this group
#pragma unroll
                for (int ni = 0; ni < 4; ++ni)
#pragma unroll
                    for (int r = 0; r < 4; ++r)
                        if (ni * 16 + quad * 4 + r > w * 16 + l16) s[ni][r] = -3.0e38f;
            }
            __bf16* Psw = &Ps[w][g][0];
            float la = 0.f;
#pragma unroll
            for (int ni = 0; ni < 4; ++ni) {
                __bf16 pb[4];
#pragma unroll
                for (int r = 0; r < 4; ++r) {
                    float pe = __builtin_amdgcn_exp2f(s[ni][r] * SC);
                    la += pe;
                    pb[r] = (__bf16)pe;
                }
                int seg = (ni * 2 + (quad >> 1)) ^ lxor;
                *(uint2*)&Psw[l16 * 64 + seg * 8 + (quad & 1) * 4] = *(uint2*)pb;
            }
            lacc[g] += la;
        }
        __threadfence_block();   // wave-private P write->read ordering

        // ---- O += P V (V fragments shared across groups) ----
#pragma unroll
        for (int ni = 0; ni < 4; ++ni) {
#pragma unroll
            for (int kk = 0; kk < 2; ++kk) {
                bf16x8 vf = *(const bf16x8*)&Vs[(ni * 16 + l16) * 64 +
                                                (((kk * 4 + quad) ^ lxor) * 8)];
#pragma unroll
                for (int g = 0; g < 2; ++g) {
                    if (g == 0 && kt == nkt - 1) continue;
                    bf16x8 pf = *(const bf16x8*)&Ps[w][g][l16 * 64 +
                                                        (((kk * 4 + quad) ^ lxor) * 8)];
                    o[g][ni] = __builtin_amdgcn_mfma_f32_16x16x32_bf16(pf, vf, o[g][ni], 0, 0, 0);
                }
            }
        }
        __syncthreads();   // buffers consumed; prefetched tile drained
    }

    // ---- epilogue per group ----
#pragma unroll
    for (int g = 0; g < 2; ++g) {
        float la = lacc[g];
        la += __shfl_xor(la, 16, 64);
        la += __shfl_xor(la, 32, 64);
#pragma unroll
        for (int r = 0; r < 4; ++r) {
            float linv = 1.f / __shfl(la, quad * 4 + r, 64);
            int trow = qt * 128 + g * 64 + w * 16 + quad * 4 + r;
#pragma unroll
            for (int ni = 0; ni < 4; ++ni)
                out[((size_t)(b * T_ + trow)) * C_ + h * 64 + ni * 16 + l16] =
                    (__bf16)(o[g][ni][r] * linv);
        }
    }
}

// ---------------------------------------------------------------------------
extern "C" void kernel_launch(void* const* d_in, const int* in_sizes, int n_in,
                              void* d_out, int out_size, void* d_ws, size_t ws_size,
                              hipStream_t stream)
{
    const float* x     = (const float*)d_in[0];
    const float* Wqkv  = (const float*)d_in[1];
    const float* bqkv  = (const float*)d_in[2];
    const float* Wproj = (const float*)d_in[3];
    const float* bproj = (const float*)d_in[4];
    float* out = (float*)d_out;

    char* ws = (char*)d_ws;
    __bf16* xb     = (__bf16*)(ws);                 //  8 MB [4096,1024] (reused as att)
    __bf16* Wqkvt  = (__bf16*)(ws + (8u  << 20));   //  6 MB [3072,1024]
    __bf16* Wprojt = (__bf16*)(ws + (14u << 20));   //  2 MB [1024,1024]
    __bf16* qk     = (__bf16*)(ws + (16u << 20));   // 16 MB [4096,2048]
    __bf16* vt     = (__bf16*)(ws + (32u << 20));   //  8 MB [B*C,2048]
    __bf16* att    = xb;                            // alias: xb dead after GEMM1

    conv_bf16<<<(M_ROWS * C_ / 8 + 255) / 256, 256, 0, stream>>>(x, xb, M_ROWS * C_ / 8);
    transp_w2<<<dim3(16, 64), 256, 0, stream>>>(Wqkv, Wproj, Wqkvt, Wprojt);

    gemm_qkv<<<dim3(M_ROWS / 128, N_QKV / 128), 256, 0, stream>>>(
        xb, Wqkvt, bqkv, qk, vt);

    attn_kernel<<<dim3(32, 16), 256, 0, stream>>>(qk, vt, att);

    gemm_proj<<<dim3(M_ROWS / 128, C_ / 128), 256, 0, stream>>>(
        att, Wprojt, bproj, out);
}

// Round 5
// 175.375 us; speedup vs baseline: 1.0952x; 1.0952x over previous
//
#include <hip/hip_runtime.h>
#include <hip/hip_bf16.h>

// Problem constants
#define B_ 2
#define T_ 2048
#define C_ 1024
#define H_ 16
#define D_ 64
#define M_ROWS (B_ * T_)      // 4096
#define N_QKV (3 * C_)        // 3072
#define QKS (2 * C_)          // q/k buffer row stride = 2048

typedef __bf16 bf16x8 __attribute__((ext_vector_type(8)));
typedef float f32x4 __attribute__((ext_vector_type(4)));

// 0.125 (1/sqrt(64)) * log2(e): softmax in base-2, scale folded in.
#define SC 0.18033688011112042f

// async global->LDS, 16B per lane. LDS dest = wave-uniform base + lane*16.
__device__ __forceinline__ void gl_lds16(const __bf16* g, __bf16* l) {
    __builtin_amdgcn_global_load_lds(
        (const __attribute__((address_space(1))) unsigned int*)g,
        (__attribute__((address_space(3))) unsigned int*)l, 16, 0, 0);
}

// ---------------------------------------------------------------------------
// Pre-pass 1: fp32 -> bf16 convert (x -> xb). 8 elems/thread.
// ---------------------------------------------------------------------------
__global__ __launch_bounds__(256) void conv_bf16(const float* __restrict__ in,
                                                 __bf16* __restrict__ out, int n8)
{
    int i = blockIdx.x * 256 + threadIdx.x;
    if (i >= n8) return;
    const float4* p = (const float4*)(in + (size_t)i * 8);
    float4 a = p[0], b = p[1];
    __bf16 v[8] = {(__bf16)a.x, (__bf16)a.y, (__bf16)a.z, (__bf16)a.w,
                   (__bf16)b.x, (__bf16)b.y, (__bf16)b.z, (__bf16)b.w};
    *(uint4*)(out + (size_t)i * 8) = *(uint4*)v;
}

// ---------------------------------------------------------------------------
// Pre-pass 2 (merged): both weights [K][N] fp32 -> [N][K] bf16.
// grid (16, 64): y<48 -> Wqkv (N=3072), else Wproj (N=1024). K=1024.
// ---------------------------------------------------------------------------
__global__ __launch_bounds__(256) void transp_w2(
    const float* __restrict__ Wqkv, const float* __restrict__ Wproj,
    __bf16* __restrict__ Wqkvt, __bf16* __restrict__ Wprojt)
{
    __shared__ __bf16 Ts[64 * 72];
    const int tid = threadIdx.x;
    const int gy = blockIdx.y;
    const float* W; __bf16* Wt; int N, n0;
    if (gy < 48) { W = Wqkv;  Wt = Wqkvt;  N = N_QKV; n0 = gy * 64; }
    else         { W = Wproj; Wt = Wprojt; N = C_;    n0 = (gy - 48) * 64; }
    const int k0 = blockIdx.x * 64;
#pragma unroll
    for (int i = 0; i < 4; ++i) {
        int f = i * 256 + tid;
        int r = f >> 4, c4 = (f & 15) * 4;
        float4 v = *(const float4*)(W + (size_t)(k0 + r) * N + n0 + c4);
        Ts[(c4 + 0) * 72 + r] = (__bf16)v.x;
        Ts[(c4 + 1) * 72 + r] = (__bf16)v.y;
        Ts[(c4 + 2) * 72 + r] = (__bf16)v.z;
        Ts[(c4 + 3) * 72 + r] = (__bf16)v.w;
    }
    __syncthreads();
#pragma unroll
    for (int i = 0; i < 2; ++i) {
        int f = i * 256 + tid;
        int n = f >> 3, c8 = (f & 7) * 8;
        *(uint4*)(Wt + (size_t)(n0 + n) * C_ + k0 + c8) = *(const uint4*)&Ts[n * 72 + c8];
    }
}

// ---------------------------------------------------------------------------
// GEMM1 (fused): qkv = xb @ Wqkvt^T + bqkv.
// q,k columns -> qk buffer [4096, 2048] bf16; v columns -> vt [B*C][T] bf16
// transposed directly from the C/D fragment (lane holds fixed col, 4 rows).
// ---------------------------------------------------------------------------
#define GBK 64

__global__ __launch_bounds__(256) void gemm_qkv(
    const __bf16* __restrict__ A, const __bf16* __restrict__ Bt,
    const float* __restrict__ bias, __bf16* __restrict__ qk,
    __bf16* __restrict__ vt)
{
    __shared__ __bf16 As[128 * GBK];
    __shared__ __bf16 Bs[128 * GBK];

    const int tid  = threadIdx.x;
    const int m0   = blockIdx.x * 128;
    const int n0   = blockIdx.y * 128;
    const int w    = tid >> 6;
    const int lane = tid & 63;
    const int quad = lane >> 4;
    const int l16  = lane & 15;
    const int wr   = (w >> 1) * 64;
    const int wc   = (w & 1) * 64;
    const int K = C_;

    const int srow = w * 32 + (lane >> 3);
    const int sseg = ((lane & 7) ^ (lane >> 3)) * 8;
    const __bf16* Ag = A + (size_t)(m0 + srow) * K + sseg;
    const __bf16* Bg = Bt + (size_t)(n0 + srow) * K + sseg;

    f32x4 acc[4][4] = {};

    for (int k0 = 0; k0 < K; k0 += GBK) {
#pragma unroll
        for (int i = 0; i < 4; ++i) {
            gl_lds16(Ag + k0 + (size_t)(i * 8) * K, &As[(w * 32 + i * 8) * GBK]);
            gl_lds16(Bg + k0 + (size_t)(i * 8) * K, &Bs[(w * 32 + i * 8) * GBK]);
        }
        __syncthreads();
#pragma unroll
        for (int kk = 0; kk < 2; ++kk) {
            bf16x8 af[4], bf[4];
#pragma unroll
            for (int mi = 0; mi < 4; ++mi)
                af[mi] = *(const bf16x8*)&As[(wr + mi * 16 + l16) * GBK +
                                             (((kk * 4 + quad) ^ (l16 & 7)) * 8)];
#pragma unroll
            for (int ni = 0; ni < 4; ++ni)
                bf[ni] = *(const bf16x8*)&Bs[(wc + ni * 16 + l16) * GBK +
                                             (((kk * 4 + quad) ^ (l16 & 7)) * 8)];
#pragma unroll
            for (int mi = 0; mi < 4; ++mi)
#pragma unroll
                for (int ni = 0; ni < 4; ++ni)
                    acc[mi][ni] = __builtin_amdgcn_mfma_f32_16x16x32_bf16(
                        af[mi], bf[ni], acc[mi][ni], 0, 0, 0);
        }
        __syncthreads();
    }

    if (n0 < 2 * C_) {
        // q/k: row-major store into qk (stride 2048)
#pragma unroll
        for (int mi = 0; mi < 4; ++mi) {
#pragma unroll
            for (int ni = 0; ni < 4; ++ni) {
                int col = n0 + wc + ni * 16 + l16;
                float bv = bias[col];
#pragma unroll
                for (int r = 0; r < 4; ++r) {
                    int row = m0 + wr + mi * 16 + quad * 4 + r;
                    qk[(size_t)row * QKS + col] = (__bf16)(acc[mi][ni][r] + bv);
                }
            }
        }
    } else {
        // v: transposed store into vt[(b*C + c)][t]
        const int bb = m0 >> 11;
        const int tb = (m0 & (T_ - 1)) + wr;
#pragma unroll
        for (int mi = 0; mi < 4; ++mi) {
#pragma unroll
            for (int ni = 0; ni < 4; ++ni) {
                int col = n0 + wc + ni * 16 + l16;
                float bv = bias[col];
                int c = col - 2 * C_;
                int t0 = tb + mi * 16 + quad * 4;
                __bf16 pb[4];
#pragma unroll
                for (int r = 0; r < 4; ++r)
                    pb[r] = (__bf16)(acc[mi][ni][r] + bv);
                *(uint2*)&vt[((size_t)bb * C_ + c) * T_ + t0] = *(uint2*)pb;
            }
        }
    }
}

// ---------------------------------------------------------------------------
// GEMM2: out = att @ Wprojt^T + bproj (fp32 out).
// ---------------------------------------------------------------------------
__global__ __launch_bounds__(256) void gemm_proj(
    const __bf16* __restrict__ A, const __bf16* __restrict__ Bt,
    const float* __restrict__ bias, float* __restrict__ C)
{
    __shared__ __bf16 As[128 * GBK];
    __shared__ __bf16 Bs[128 * GBK];

    const int tid  = threadIdx.x;
    const int m0   = blockIdx.x * 128;
    const int n0   = blockIdx.y * 128;
    const int w    = tid >> 6;
    const int lane = tid & 63;
    const int quad = lane >> 4;
    const int l16  = lane & 15;
    const int wr   = (w >> 1) * 64;
    const int wc   = (w & 1) * 64;
    const int K = C_, N = C_;

    const int srow = w * 32 + (lane >> 3);
    const int sseg = ((lane & 7) ^ (lane >> 3)) * 8;
    const __bf16* Ag = A + (size_t)(m0 + srow) * K + sseg;
    const __bf16* Bg = Bt + (size_t)(n0 + srow) * K + sseg;

    f32x4 acc[4][4] = {};

    for (int k0 = 0; k0 < K; k0 += GBK) {
#pragma unroll
        for (int i = 0; i < 4; ++i) {
            gl_lds16(Ag + k0 + (size_t)(i * 8) * K, &As[(w * 32 + i * 8) * GBK]);
            gl_lds16(Bg + k0 + (size_t)(i * 8) * K, &Bs[(w * 32 + i * 8) * GBK]);
        }
        __syncthreads();
#pragma unroll
        for (int kk = 0; kk < 2; ++kk) {
            bf16x8 af[4], bf[4];
#pragma unroll
            for (int mi = 0; mi < 4; ++mi)
                af[mi] = *(const bf16x8*)&As[(wr + mi * 16 + l16) * GBK +
                                             (((kk * 4 + quad) ^ (l16 & 7)) * 8)];
#pragma unroll
            for (int ni = 0; ni < 4; ++ni)
                bf[ni] = *(const bf16x8*)&Bs[(wc + ni * 16 + l16) * GBK +
                                             (((kk * 4 + quad) ^ (l16 & 7)) * 8)];
#pragma unroll
            for (int mi = 0; mi < 4; ++mi)
#pragma unroll
                for (int ni = 0; ni < 4; ++ni)
                    acc[mi][ni] = __builtin_amdgcn_mfma_f32_16x16x32_bf16(
                        af[mi], bf[ni], acc[mi][ni], 0, 0, 0);
        }
        __syncthreads();
    }

#pragma unroll
    for (int mi = 0; mi < 4; ++mi) {
#pragma unroll
        for (int ni = 0; ni < 4; ++ni) {
            int col = n0 + wc + ni * 16 + l16;
            float bv = bias[col];
#pragma unroll
            for (int r = 0; r < 4; ++r) {
                int row = m0 + wr + mi * 16 + quad * 4 + r;
                C[(size_t)row * N + col] = acc[mi][ni][r] + bv;
            }
        }
    }
}

// ---------------------------------------------------------------------------
// Flash attention v5: R3's balanced structure (64-q tiles, complementary
// pairs -> every block exactly 33 K-iters, 48 KB LDS, 512 blocks = 512
// slots) + R4's XCD pinning (blockIdx.x = bh -> XCD = bh%8; 4 heads/XCD,
// 2 MB K+V resident in per-XCD L2). No-max base-2 softmax, S^T trick,
// double-buffered K/V staging, 1 barrier per K-tile, hoisted Q fragments.
// ---------------------------------------------------------------------------
__global__ __launch_bounds__(256) void attn_kernel(
    const __bf16* __restrict__ qk, const __bf16* __restrict__ vt,
    __bf16* __restrict__ out)
{
    __shared__ __bf16 Qs[64 * 64];
    __shared__ __bf16 KVs[4][64 * 64];   // K0,V0,K1,V1 (double buffer)
    __shared__ __bf16 Ps[4][16 * 64];    // per-wave P, XOR-swizzled

    const int tid  = threadIdx.x;
    const int bh   = blockIdx.x;          // 0..31 -> XCD = bh % 8 (pinned)
    const int p    = blockIdx.y;          // 0..15 (pair index)
    const int b    = bh >> 4;
    const int h    = bh & 15;
    const int w    = tid >> 6;
    const int lane = tid & 63;
    const int quad = lane >> 4;
    const int l16  = lane & 15;
    const int lxor = l16 & 7;

    const int srow = lane >> 3;
    const int sseg = ((lane & 7) ^ srow) * 8;
    __bf16* Psw = &Ps[w][0];

    for (int half = 0; half < 2; ++half) {
        const int qt = half ? (31 - p) : p;

        // ---- stage Q tile + K/V tile 0 ----
        {
            const __bf16* Qg = qk + (size_t)(b * T_ + qt * 64 + w * 16 + srow) * QKS
                             + (size_t)h * 64 + sseg;
            gl_lds16(Qg, &Qs[(w * 16) * 64]);
            gl_lds16(Qg + (size_t)8 * QKS, &Qs[(w * 16 + 8) * 64]);
            const __bf16* Kg = qk + (size_t)(b * T_ + w * 16 + srow) * QKS
                             + C_ + (size_t)h * 64 + sseg;
            gl_lds16(Kg, &KVs[0][(w * 16) * 64]);
            gl_lds16(Kg + (size_t)8 * QKS, &KVs[0][(w * 16 + 8) * 64]);
            const __bf16* Vg = vt + ((size_t)(b * H_ + h) * 64 + w * 16 + srow) * T_ + sseg;
            gl_lds16(Vg, &KVs[1][(w * 16) * 64]);
            gl_lds16(Vg + (size_t)8 * T_, &KVs[1][(w * 16 + 8) * 64]);
        }
        __syncthreads();

        // ---- hoist Q fragments (B-operand: n = q = w*16+l16, k = d) ----
        bf16x8 qf[2];
#pragma unroll
        for (int kk = 0; kk < 2; ++kk)
            qf[kk] = *(const bf16x8*)&Qs[(w * 16 + l16) * 64 + (((kk * 4 + quad) ^ lxor) * 8)];

        f32x4 o[4] = {};
        float lacc = 0.f;

        for (int kt = 0; kt <= qt; ++kt) {
            const __bf16* Ks = KVs[(kt & 1) * 2];
            const __bf16* Vs = KVs[(kt & 1) * 2 + 1];

            // prefetch next K/V tile into other buffer (async, drains at barrier)
            if (kt < qt) {
                int nb = ((kt + 1) & 1) * 2;
                const __bf16* Kg = qk + (size_t)(b * T_ + (kt + 1) * 64 + w * 16 + srow) * QKS
                                 + C_ + (size_t)h * 64 + sseg;
                gl_lds16(Kg, &KVs[nb][(w * 16) * 64]);
                gl_lds16(Kg + (size_t)8 * QKS, &KVs[nb][(w * 16 + 8) * 64]);
                const __bf16* Vg = vt + ((size_t)(b * H_ + h) * 64 + w * 16 + srow) * T_
                                 + (kt + 1) * 64 + sseg;
                gl_lds16(Vg, &KVs[nb + 1][(w * 16) * 64]);
                gl_lds16(Vg + (size_t)8 * T_, &KVs[nb + 1][(w * 16 + 8) * 64]);
            }

            // ---- S^T = K Q^T: lane holds q = w*16+l16 (col), keys ni*16+quad*4+r (row)
            f32x4 s[4] = {};
#pragma unroll
            for (int ni = 0; ni < 4; ++ni) {
#pragma unroll
                for (int kk = 0; kk < 2; ++kk) {
                    bf16x8 kf = *(const bf16x8*)&Ks[(ni * 16 + l16) * 64 +
                                                    (((kk * 4 + quad) ^ lxor) * 8)];
                    s[ni] = __builtin_amdgcn_mfma_f32_16x16x32_bf16(kf, qf[kk], s[ni], 0, 0, 0);
                }
            }

            // ---- causal mask (diag tile only): key > q -> -inf ----
            if (kt == qt) {
#pragma unroll
                for (int ni = 0; ni < 4; ++ni)
#pragma unroll
                    for (int r = 0; r < 4; ++r)
                        if (ni * 16 + quad * 4 + r > w * 16 + l16) s[ni][r] = -3.0e38f;
            }

            // ---- p = 2^(s*SC); accumulate l; pack to bf16; write P to LDS ----
#pragma unroll
            for (int ni = 0; ni < 4; ++ni) {
                __bf16 pb[4];
#pragma unroll
                for (int r = 0; r < 4; ++r) {
                    float pe = __builtin_amdgcn_exp2f(s[ni][r] * SC);
                    lacc += pe;
                    pb[r] = (__bf16)pe;
                }
                int seg = (ni * 2 + (quad >> 1)) ^ lxor;
                *(uint2*)&Psw[l16 * 64 + seg * 8 + (quad & 1) * 4] = *(uint2*)pb;
            }
            __threadfence_block();   // wave-private write->read ordering (lgkmcnt)

            // ---- O += P V ----
            bf16x8 pf[2];
#pragma unroll
            for (int kk = 0; kk < 2; ++kk)
                pf[kk] = *(const bf16x8*)&Psw[l16 * 64 + (((kk * 4 + quad) ^ lxor) * 8)];
#pragma unroll
            for (int ni = 0; ni < 4; ++ni) {
#pragma unroll
                for (int kk = 0; kk < 2; ++kk) {
                    bf16x8 vf = *(const bf16x8*)&Vs[(ni * 16 + l16) * 64 +
                                                    (((kk * 4 + quad) ^ lxor) * 8)];
                    o[ni] = __builtin_amdgcn_mfma_f32_16x16x32_bf16(pf[kk], vf, o[ni], 0, 0, 0);
                }
            }
            __syncthreads();   // buffers consumed; prefetched tile drained
        }

        // ---- reduce l across quads (q = w*16+l16 lane-constant) ----
        lacc += __shfl_xor(lacc, 16, 64);
        lacc += __shfl_xor(lacc, 32, 64);

        // ---- epilogue: O row q = w*16+quad*4+r, col d = ni*16+l16 ----
#pragma unroll
        for (int r = 0; r < 4; ++r) {
            float linv = 1.f / __shfl(lacc, quad * 4 + r, 64);
            int trow = qt * 64 + w * 16 + quad * 4 + r;
#pragma unroll
            for (int ni = 0; ni < 4; ++ni)
                out[((size_t)(b * T_ + trow)) * C_ + h * 64 + ni * 16 + l16] =
                    (__bf16)(o[ni][r] * linv);
        }
        // no barrier needed: next half's staging only writes LDS regions that
        // no wave reads until after the post-stage __syncthreads
    }
}

// ---------------------------------------------------------------------------
extern "C" void kernel_launch(void* const* d_in, const int* in_sizes, int n_in,
                              void* d_out, int out_size, void* d_ws, size_t ws_size,
                              hipStream_t stream)
{
    const float* x     = (const float*)d_in[0];
    const float* Wqkv  = (const float*)d_in[1];
    const float* bqkv  = (const float*)d_in[2];
    const float* Wproj = (const float*)d_in[3];
    const float* bproj = (const float*)d_in[4];
    float* out = (float*)d_out;

    char* ws = (char*)d_ws;
    __bf16* xb     = (__bf16*)(ws);                 //  8 MB [4096,1024] (reused as att)
    __bf16* Wqkvt  = (__bf16*)(ws + (8u  << 20));   //  6 MB [3072,1024]
    __bf16* Wprojt = (__bf16*)(ws + (14u << 20));   //  2 MB [1024,1024]
    __bf16* qk     = (__bf16*)(ws + (16u << 20));   // 16 MB [4096,2048]
    __bf16* vt     = (__bf16*)(ws + (32u << 20));   //  8 MB [B*C,2048]
    __bf16* att    = xb;                            // alias: xb dead after GEMM1

    conv_bf16<<<(M_ROWS * C_ / 8 + 255) / 256, 256, 0, stream>>>(x, xb, M_ROWS * C_ / 8);
    transp_w2<<<dim3(16, 64), 256, 0, stream>>>(Wqkv, Wproj, Wqkvt, Wprojt);

    gemm_qkv<<<dim3(M_ROWS / 128, N_QKV / 128), 256, 0, stream>>>(
        xb, Wqkvt, bqkv, qk, vt);

    // balanced pairs on y, XCD-pinned heads on x
    attn_kernel<<<dim3(32, 16), 256, 0, stream>>>(qk, vt, att);

    gemm_proj<<<dim3(M_ROWS / 128, C_ / 128), 256, 0, stream>>>(
        att, Wprojt, bproj, out);
}